// Round 3
// baseline (24.093 us; speedup 1.0000x reference)
//
#include <hip/hip_runtime.h>

#define KS   7
#define KK   49
#define MIDJ 24
#define H    256
#define W    320
#define HW   (H * W)
#define BS   4
#define ITERS 6

// Padded input geometry: 3 halo rows top/bottom, left pad 4, right pad 4.
#define PH   (H + 6)      // 262
#define PW   (W + 8)      // 328 row stride
#define XOFF 4            // x maps to column x+4
#define PAD_ELEMS (BS * PH * PW)   // 343744

// ---------------------------------------------------------------------------
// Pre-kernel: build zero-padded copy of `input` in workspace.
__global__ __launch_bounds__(256) void pad_kernel(
    const float* __restrict__ input,   // (BS, H, W)
    float*       __restrict__ pad)     // (BS, PH, PW)
{
    int idx = blockIdx.x * blockDim.x + threadIdx.x;
    if (idx >= PAD_ELEMS) return;
    int b  = idx / (PH * PW);
    int r  = idx - b * (PH * PW);
    int yp = r / PW;
    int xp = r - yp * PW;
    int y  = yp - 3;
    int x  = xp - XOFF;
    float v = 0.f;
    if (y >= 0 && y < H && x >= 0 && x < W)
        v = input[(size_t)b * HW + y * W + x];
    pad[idx] = v;
}

// ---------------------------------------------------------------------------
// Main fused kernel: 4 pixels/thread, all loads float4 (1 KB/wave/instr).
// Neighbor taps come from a 12-float sliding window per kernel row; all
// selection indices are compile-time so everything stays in registers.
__global__ __launch_bounds__(64) void dyspn_kernel(
    const float* __restrict__ kern,    // (BS, KK, HW)
    const float* __restrict__ pad,     // (BS, PH, PW)
    const float* __restrict__ input0,  // (BS, H, W)
    const float* __restrict__ att,     // (BS, ITERS, 4, HW)
    const int*   __restrict__ i_ptr,   // scalar
    float*       __restrict__ out)     // (BS, H, W)
{
    const int i_sel = *i_ptr;

    int t   = blockIdx.x * 64 + threadIdx.x;  // 0 .. 81919
    int idx = t * 4;                          // first of 4 pixels
    int b = idx / HW;
    int p = idx - b * HW;                     // multiple of 4
    int y = p / W;
    int x = p - y * W;                        // multiple of 4 (W%4==0)

    // attention[b, i_sel, 0..3, p..p+3]
    const float* attb = att + ((size_t)(b * ITERS + i_sel)) * 4 * HW + p;
    float4 a0 = *(const float4*)(attb);
    float4 a1 = *(const float4*)(attb + HW);
    float4 a2 = *(const float4*)(attb + 2 * HW);
    float4 a3 = *(const float4*)(attb + 3 * HW);
    const float ar[4][4] = {{a0.x, a0.y, a0.z, a0.w},
                            {a1.x, a1.y, a1.z, a1.w},
                            {a2.x, a2.y, a2.z, a2.w},
                            {a3.x, a3.y, a3.z, a3.w}};

    const float* kb   = kern + (size_t)b * KK * HW + p;
    const float* prow = pad + (size_t)b * PH * PW + (y + 3) * PW + (x + XOFF);

    float4 mid4 = *(const float4*)(input0 + (size_t)b * HW + p);
    const float mid[4] = {mid4.x, mid4.y, mid4.z, mid4.w};

    float acc[4] = {0.f, 0.f, 0.f, 0.f};
    float den[4] = {0.f, 0.f, 0.f, 0.f};

#pragma unroll
    for (int jr = 0; jr < KS; ++jr) {
        const int dy = jr - 3;                       // compile-time
        // 12-float window: pad cols (x+XOFF-4) .. (x+XOFF+7), row y+3+dy
        float v[12];
        const float* r0 = prow + dy * PW - 4;        // 16B aligned
        *(float4*)&v[0] = *(const float4*)(r0);
        *(float4*)&v[4] = *(const float4*)(r0 + 4);
        *(float4*)&v[8] = *(const float4*)(r0 + 8);

#pragma unroll
        for (int jc = 0; jc < KS; ++jc) {
            const int j  = jr * KS + jc;
            const int dx = jc - 3;                   // compile-time
            const int r  = max(dy < 0 ? -dy : dy,
                               dx < 0 ? -dx : dx);   // ring id, compile-time

            float4 kv = *(const float4*)(kb + (size_t)j * HW);
            const float kq[4] = {kv.x, kv.y, kv.z, kv.w};
#pragma unroll
            for (int q = 0; q < 4; ++q) {
                float val = kq[q] * ar[r][q];
                den[q] += fabsf(val);
                float pv = (j == MIDJ) ? mid[q] : v[4 + dx + q];  // compile-time idx 1..10
                acc[q] = fmaf(val, pv, acc[q]);
            }
        }
    }

    float4 o;
    o.x = acc[0] / den[0];
    o.y = acc[1] / den[1];
    o.z = acc[2] / den[2];
    o.w = acc[3] / den[3];
    *(float4*)(out + (size_t)b * HW + p) = o;
}

extern "C" void kernel_launch(void* const* d_in, const int* in_sizes, int n_in,
                              void* d_out, int out_size, void* d_ws, size_t ws_size,
                              hipStream_t stream) {
    const float* kern   = (const float*)d_in[0];
    const float* input  = (const float*)d_in[1];
    const float* input0 = (const float*)d_in[2];
    const float* att    = (const float*)d_in[3];
    const int*   i_ptr  = (const int*)d_in[4];
    float* out = (float*)d_out;

    const size_t pad_bytes = (size_t)PAD_ELEMS * sizeof(float);
    (void)pad_bytes;

    float* pad = (float*)d_ws;
    const int grid_pad = (PAD_ELEMS + 255) / 256;            // 1343
    pad_kernel<<<grid_pad, 256, 0, stream>>>(input, pad);

    const int threads = BS * HW / 4;                         // 81920
    const int grid_main = threads / 64;                      // 1280 blocks = 5 waves/CU
    dyspn_kernel<<<grid_main, 64, 0, stream>>>(kern, pad, input0, att, i_ptr, out);
}